// Round 2
// baseline (824.835 us; speedup 1.0000x reference)
//
#include <hip/hip_runtime.h>
#include <hip/hip_bf16.h>

typedef __bf16 bf16_t;
typedef __bf16 bf16x8 __attribute__((ext_vector_type(8)));
typedef __bf16 bf16x4 __attribute__((ext_vector_type(4)));
typedef float f32x4 __attribute__((ext_vector_type(4)));

#define NB 16384
#define PP 128

__device__ inline bf16x8 ld8(const bf16_t* p) { return *(const bf16x8*)p; }

// direct global->LDS async copy, 16 bytes per lane (wave-uniform LDS base + lane*16)
__device__ inline void gload_lds16(const bf16_t* g, bf16_t* l) {
  __builtin_amdgcn_global_load_lds(
      (const __attribute__((address_space(1))) unsigned int*)g,
      (__attribute__((address_space(3))) unsigned int*)l, 16, 0, 0);
}

// ---------------------------------------------------------------------------
// K1: out[n*K + k] = (bf16) in[k*N + n]   (transpose + fp32->bf16)
// ---------------------------------------------------------------------------
__global__ void transpose_convert(const float* __restrict__ in, bf16_t* __restrict__ out,
                                  int K, int N) {
  int idx = blockIdx.x * 256 + threadIdx.x;
  if (idx >= K * N) return;
  int k = idx / N, n = idx - k * N;
  out[n * K + k] = (bf16_t)in[idx];
}

// ---------------------------------------------------------------------------
// K2: H = relu(X @ W1 + b1) in bf16.  X:[NB][K] fp32, Wt:[128][K] bf16 (pre-transposed)
// block = 256 thr (4 waves), BM=64, BN=128, BK=64. LDS XOR-swizzled (chunk^(row&7)).
// ---------------------------------------------------------------------------
__global__ __launch_bounds__(256, 2) void mlp1_kernel(
    const float* __restrict__ X, const bf16_t* __restrict__ Wt,
    const float* __restrict__ bias, bf16_t* __restrict__ H, int K) {
  __shared__ bf16_t As[64 * 64];    // row r: 8 chunks of 8 bf16, chunk stored at (c^(r&7))
  __shared__ bf16_t Bs[128 * 64];
  const int t = threadIdx.x, l = t & 63, wid = t >> 6;
  const int wm = wid >> 1, wn = wid & 1;          // wave tile 32x64
  const int row0 = blockIdx.x * 64;

  f32x4 acc[2][4];
#pragma unroll
  for (int i = 0; i < 2; i++)
#pragma unroll
    for (int j = 0; j < 4; j++) acc[i][j] = (f32x4){0.f, 0.f, 0.f, 0.f};

  for (int k0 = 0; k0 < K; k0 += 64) {
    __syncthreads();
    // stage A: 64 rows x 64 fp32 -> bf16. 1024 quad-slots (4 floats each)
#pragma unroll
    for (int i = 0; i < 4; i++) {
      int s = t + i * 256;
      int r = s >> 4, c4 = s & 15;                 // quad index
      const float4 f = *(const float4*)(X + (size_t)(row0 + r) * K + k0 + c4 * 4);
      bf16x4 pk;
      pk[0] = (bf16_t)f.x; pk[1] = (bf16_t)f.y; pk[2] = (bf16_t)f.z; pk[3] = (bf16_t)f.w;
      int chunk = c4 >> 1, half = c4 & 1;
      *(bf16x4*)(As + r * 64 + (chunk ^ (r & 7)) * 8 + half * 4) = pk;
    }
    // stage B: 128 rows x 64 bf16. 1024 chunk-slots
#pragma unroll
    for (int i = 0; i < 4; i++) {
      int s = t + i * 256;
      int r = s >> 3, c = s & 7;
      bf16x8 v = ld8(Wt + (size_t)r * K + k0 + c * 8);
      *(bf16x8*)(Bs + r * 64 + (c ^ (r & 7)) * 8) = v;
    }
    __syncthreads();
#pragma unroll
    for (int ks = 0; ks < 2; ks++) {
      bf16x8 a[2];
#pragma unroll
      for (int mt = 0; mt < 2; mt++) {
        int r = wm * 32 + mt * 16 + (l & 15);
        int c = ks * 4 + (l >> 4);
        a[mt] = ld8(As + r * 64 + (c ^ (r & 7)) * 8);
      }
#pragma unroll
      for (int nt = 0; nt < 4; nt++) {
        int rb = wn * 64 + nt * 16 + (l & 15);
        int c = ks * 4 + (l >> 4);
        bf16x8 b = ld8(Bs + rb * 64 + (c ^ (rb & 7)) * 8);
#pragma unroll
        for (int mt = 0; mt < 2; mt++)
          acc[mt][nt] = __builtin_amdgcn_mfma_f32_16x16x32_bf16(a[mt], b, acc[mt][nt], 0, 0, 0);
      }
    }
  }
  // epilogue: +bias, relu, store bf16.  C/D: col=lane&15, row=(lane>>4)*4+reg
#pragma unroll
  for (int mt = 0; mt < 2; mt++) {
    int rbase = row0 + wm * 32 + mt * 16 + ((l >> 4) << 2);
#pragma unroll
    for (int nt = 0; nt < 4; nt++) {
      int col = wn * 64 + nt * 16 + (l & 15);
      float bv = bias[col];
#pragma unroll
      for (int r4 = 0; r4 < 4; r4++) {
        float v = acc[mt][nt][r4] + bv;
        H[(size_t)(rbase + r4) * PP + col] = (bf16_t)fmaxf(v, 0.f);
      }
    }
  }
}

// ---------------------------------------------------------------------------
// K3: Out = l2norm(Hin @ W2 + b2) in bf16, stored CHUNK-SWIZZLED per row:
// element (row, col) lands at col' = ((col>>3) ^ (row&7))*8 + (col&7).
// This lets K4 stage with global_load_lds (linear dest) and read with XOR.
// Hin:[NB][128] bf16, W2t:[128][128] bf16. BM=64, full K=128 staged once.
// ---------------------------------------------------------------------------
__global__ __launch_bounds__(256, 2) void mlp2_norm_kernel(
    const bf16_t* __restrict__ Hin, const bf16_t* __restrict__ W2t,
    const float* __restrict__ bias, bf16_t* __restrict__ Out) {
  __shared__ bf16_t As[64 * 128];
  __shared__ bf16_t Bs[128 * 128];
  __shared__ float rnorm[64];
  const int t = threadIdx.x, l = t & 63, wid = t >> 6;
  const int wm = wid >> 1, wn = wid & 1;
  const int row0 = blockIdx.x * 64;
  if (t < 64) rnorm[t] = 0.f;
#pragma unroll
  for (int i = 0; i < 4; i++) {  // A: 64 x 16 chunks
    int s = t + i * 256;
    int r = s >> 4, c = s & 15;
    bf16x8 v = ld8(Hin + (size_t)(row0 + r) * 128 + c * 8);
    *(bf16x8*)(As + r * 128 + (c ^ (r & 7)) * 8) = v;
  }
#pragma unroll
  for (int i = 0; i < 8; i++) {  // B: 128 x 16 chunks
    int s = t + i * 256;
    int r = s >> 4, c = s & 15;
    bf16x8 v = ld8(W2t + (size_t)r * 128 + c * 8);
    *(bf16x8*)(Bs + r * 128 + (c ^ (r & 7)) * 8) = v;
  }
  __syncthreads();
  f32x4 acc[2][4];
#pragma unroll
  for (int i = 0; i < 2; i++)
#pragma unroll
    for (int j = 0; j < 4; j++) acc[i][j] = (f32x4){0.f, 0.f, 0.f, 0.f};
#pragma unroll
  for (int ks = 0; ks < 4; ks++) {
    bf16x8 a[2];
#pragma unroll
    for (int mt = 0; mt < 2; mt++) {
      int r = wm * 32 + mt * 16 + (l & 15);
      int c = ks * 4 + (l >> 4);
      a[mt] = ld8(As + r * 128 + (c ^ (r & 7)) * 8);
    }
#pragma unroll
    for (int nt = 0; nt < 4; nt++) {
      int rb = wn * 64 + nt * 16 + (l & 15);
      int c = ks * 4 + (l >> 4);
      bf16x8 b = ld8(Bs + rb * 128 + (c ^ (rb & 7)) * 8);
#pragma unroll
      for (int mt = 0; mt < 2; mt++)
        acc[mt][nt] = __builtin_amdgcn_mfma_f32_16x16x32_bf16(a[mt], b, acc[mt][nt], 0, 0, 0);
    }
  }
  // v = acc + bias; per-row sum of squares -> rnorm (shared atomics)
  float vv[2][4][4];
#pragma unroll
  for (int mt = 0; mt < 2; mt++)
#pragma unroll
    for (int nt = 0; nt < 4; nt++) {
      int col = wn * 64 + nt * 16 + (l & 15);
      float bv = bias[col];
#pragma unroll
      for (int r4 = 0; r4 < 4; r4++) vv[mt][nt][r4] = acc[mt][nt][r4] + bv;
    }
#pragma unroll
  for (int mt = 0; mt < 2; mt++)
#pragma unroll
    for (int r4 = 0; r4 < 4; r4++) {
      float p = 0.f;
#pragma unroll
      for (int nt = 0; nt < 4; nt++) p += vv[mt][nt][r4] * vv[mt][nt][r4];
      p += __shfl_xor(p, 1); p += __shfl_xor(p, 2);
      p += __shfl_xor(p, 4); p += __shfl_xor(p, 8);
      if ((l & 15) == 0)
        atomicAdd(&rnorm[wm * 32 + mt * 16 + ((l >> 4) << 2) + r4], p);
    }
  __syncthreads();
#pragma unroll
  for (int mt = 0; mt < 2; mt++)
#pragma unroll
    for (int r4 = 0; r4 < 4; r4++) {
      int rl = wm * 32 + mt * 16 + ((l >> 4) << 2) + r4;
      float sc = 1.f / fmaxf(sqrtf(rnorm[rl]), 1e-12f);
#pragma unroll
      for (int nt = 0; nt < 4; nt++) {
        int col = wn * 64 + nt * 16 + (l & 15);
        // chunk-XOR swizzled store (key = global row & 7 == rl & 7, row0 % 64 == 0)
        int swcol = (((col >> 3) ^ (rl & 7)) << 3) | (col & 7);
        Out[(size_t)(row0 + rl) * 128 + swcol] = (bf16_t)(vv[mt][nt][r4] * sc);
      }
    }
}

// ---------------------------------------------------------------------------
// K4: fused logits + exp + row/col partial sums + diag.
// 128x128 tile per block, 4 waves (2x2, 64x64 each), K=128 single stage.
// IP/NP arrive PRE-SWIZZLED (chunk^(row&7)) so staging is linear global_load_lds
// and the MFMA read side applies the XOR.
// rowacc[i] += sum_j exp((s_ij - 1)/t); colacc[j] likewise; diag[i] = s_ii/t.
// ---------------------------------------------------------------------------
__global__ __launch_bounds__(256, 2) void logits_kernel(
    const bf16_t* __restrict__ IP, const bf16_t* __restrict__ NP,
    const float* __restrict__ log_temp, float* __restrict__ rowacc,
    float* __restrict__ colacc, float* __restrict__ diag) {
  __shared__ bf16_t As[128 * 128];
  __shared__ bf16_t Bs[128 * 128];
  // XCD-chunked bijective swizzle (16384 % 8 == 0)
  int bid = blockIdx.x;
  int sw = (bid & 7) * (NB / 128 * NB / 128 / 8) + (bid >> 3);
  int bm = sw >> 7, bn = sw & 127;
  const int t = threadIdx.x, l = t & 63, wid = t >> 6;
  const int wm = wid >> 1, wn = wid & 1;
  const float invt = __expf(-log_temp[0]);

  // stage: 32 KB per matrix, linear (data pre-swizzled at mlp2 store time).
  // thread t, iter i covers bytes [ (i*256+t)*16, +16 ): wave-uniform base + lane*16.
#pragma unroll
  for (int i = 0; i < 8; i++) {
    int s = t + i * 256;                       // 8-bf16 chunk index, 0..2047
    gload_lds16(IP + (size_t)bm * (128 * 128) + s * 8, As + s * 8);
    gload_lds16(NP + (size_t)bn * (128 * 128) + s * 8, Bs + s * 8);
  }
  __syncthreads();

  f32x4 acc[4][4];
#pragma unroll
  for (int i = 0; i < 4; i++)
#pragma unroll
    for (int j = 0; j < 4; j++) acc[i][j] = (f32x4){0.f, 0.f, 0.f, 0.f};
#pragma unroll
  for (int ks = 0; ks < 4; ks++) {
    bf16x8 a[4];
#pragma unroll
    for (int mt = 0; mt < 4; mt++) {
      int r = wm * 64 + mt * 16 + (l & 15);
      int c = ks * 4 + (l >> 4);
      a[mt] = ld8(As + r * 128 + (c ^ (r & 7)) * 8);
    }
#pragma unroll
    for (int nt = 0; nt < 4; nt++) {
      int rb = wn * 64 + nt * 16 + (l & 15);
      int c = ks * 4 + (l >> 4);
      bf16x8 b = ld8(Bs + rb * 128 + (c ^ (rb & 7)) * 8);
#pragma unroll
      for (int mt = 0; mt < 4; mt++)
        acc[mt][nt] = __builtin_amdgcn_mfma_f32_16x16x32_bf16(a[mt], b, acc[mt][nt], 0, 0, 0);
    }
  }

  const int rowbase = bm * 128 + wm * 64;
  const int colbase = bn * 128 + wn * 64;

  if (bm == bn && wm == wn) {  // diagonal cells: write s/t before exp-overwrite
#pragma unroll
    for (int mt = 0; mt < 4; mt++)
#pragma unroll
      for (int nt = 0; nt < 4; nt++)
#pragma unroll
        for (int r4 = 0; r4 < 4; r4++) {
          int gr = rowbase + mt * 16 + ((l >> 4) << 2) + r4;
          int gc = colbase + nt * 16 + (l & 15);
          if (gr == gc) diag[gr] = acc[mt][nt][r4] * invt;
        }
  }
  // overwrite acc with exp((s-1)/t)  (exact constant-shift LSE: |s|<=1)
#pragma unroll
  for (int mt = 0; mt < 4; mt++)
#pragma unroll
    for (int nt = 0; nt < 4; nt++)
#pragma unroll
      for (int r4 = 0; r4 < 4; r4++)
        acc[mt][nt][r4] = __expf((acc[mt][nt][r4] - 1.0f) * invt);
  // row partial sums: reduce over 16 lanes sharing the row
#pragma unroll
  for (int mt = 0; mt < 4; mt++)
#pragma unroll
    for (int r4 = 0; r4 < 4; r4++) {
      float rs = acc[mt][0][r4] + acc[mt][1][r4] + acc[mt][2][r4] + acc[mt][3][r4];
      rs += __shfl_xor(rs, 1); rs += __shfl_xor(rs, 2);
      rs += __shfl_xor(rs, 4); rs += __shfl_xor(rs, 8);
      if ((l & 15) == 0)
        atomicAdd(&rowacc[rowbase + mt * 16 + ((l >> 4) << 2) + r4], rs);
    }
  // col partial sums: reduce over the 4 lanes sharing the col
#pragma unroll
  for (int nt = 0; nt < 4; nt++) {
    float cs = 0.f;
#pragma unroll
    for (int mt = 0; mt < 4; mt++)
#pragma unroll
      for (int r4 = 0; r4 < 4; r4++) cs += acc[mt][nt][r4];
    cs += __shfl_xor(cs, 16); cs += __shfl_xor(cs, 32);
    if (l < 16) atomicAdd(&colacc[colbase + nt * 16 + l], cs);
  }
}

// ---------------------------------------------------------------------------
// K5: loss = 1/t + mean_i[ 0.5*(log rowacc_i + log colacc_i) - diag_i ]
// ---------------------------------------------------------------------------
__global__ void finalize_kernel(const float* __restrict__ rowacc,
                                const float* __restrict__ colacc,
                                const float* __restrict__ diag,
                                const float* __restrict__ log_temp,
                                float* __restrict__ out) {
  __shared__ float red[4];
  const int t = threadIdx.x;
  float s = 0.f;
  for (int i = t; i < NB; i += 256)
    s += 0.5f * (logf(rowacc[i]) + logf(colacc[i])) - diag[i];
  for (int m = 1; m < 64; m <<= 1) s += __shfl_xor(s, m);
  if ((t & 63) == 0) red[t >> 6] = s;
  __syncthreads();
  if (t == 0) {
    float tot = red[0] + red[1] + red[2] + red[3];
    out[0] = tot / (float)NB + expf(-log_temp[0]);
  }
}

// ---------------------------------------------------------------------------
extern "C" void kernel_launch(void* const* d_in, const int* in_sizes, int n_in,
                              void* d_out, int out_size, void* d_ws, size_t ws_size,
                              hipStream_t stream) {
  const float* img = (const float*)d_in[0];
  const float* num = (const float*)d_in[1];
  const float* Wi1 = (const float*)d_in[2];
  const float* bi1 = (const float*)d_in[3];
  const float* Wi2 = (const float*)d_in[4];
  const float* bi2 = (const float*)d_in[5];
  const float* Wn1 = (const float*)d_in[6];
  const float* bn1 = (const float*)d_in[7];
  const float* Wn2 = (const float*)d_in[8];
  const float* bn2 = (const float*)d_in[9];
  const float* log_temp = (const float*)d_in[10];
  float* out = (float*)d_out;

  char* w = (char*)d_ws;
  bf16_t* ipb   = (bf16_t*)(w);                               // 4 MB (chunk-swizzled)
  bf16_t* npb   = (bf16_t*)(w + (4u << 20));                  // 4 MB (chunk-swizzled)
  bf16_t* h_img = (bf16_t*)(w + (8u << 20));                  // 4 MB
  bf16_t* h_num = (bf16_t*)(w + (12u << 20));                 // 4 MB
  bf16_t* Wi1t  = (bf16_t*)(w + (16u << 20));                 // 512 KB [128][2048]
  bf16_t* Wn1t  = (bf16_t*)(w + (16u << 20) + (512u << 10));  // 64 KB  [128][256]
  bf16_t* Wi2t  = (bf16_t*)(w + (16u << 20) + (576u << 10));  // 32 KB  [128][128]
  bf16_t* Wn2t  = (bf16_t*)(w + (16u << 20) + (640u << 10));  // 32 KB
  float* rowacc = (float*)(w + (17u << 20));
  float* colacc = rowacc + NB;
  float* diag   = colacc + NB;

  hipMemsetAsync(rowacc, 0, 2 * NB * sizeof(float), stream);

  transpose_convert<<<dim3((2048 * 128) / 256), 256, 0, stream>>>(Wi1, Wi1t, 2048, 128);
  transpose_convert<<<dim3((256 * 128) / 256), 256, 0, stream>>>(Wn1, Wn1t, 256, 128);
  transpose_convert<<<dim3((128 * 128) / 256), 256, 0, stream>>>(Wi2, Wi2t, 128, 128);
  transpose_convert<<<dim3((128 * 128) / 256), 256, 0, stream>>>(Wn2, Wn2t, 128, 128);

  mlp1_kernel<<<dim3(NB / 64), 256, 0, stream>>>(img, Wi1t, bi1, h_img, 2048);
  mlp1_kernel<<<dim3(NB / 64), 256, 0, stream>>>(num, Wn1t, bn1, h_num, 256);
  mlp2_norm_kernel<<<dim3(NB / 64), 256, 0, stream>>>(h_img, Wi2t, bi2, ipb);
  mlp2_norm_kernel<<<dim3(NB / 64), 256, 0, stream>>>(h_num, Wn2t, bn2, npb);

  logits_kernel<<<dim3((NB / 128) * (NB / 128)), 256, 0, stream>>>(
      ipb, npb, log_temp, rowacc, colacc, diag);
  finalize_kernel<<<dim3(1), 256, 0, stream>>>(rowacc, colacc, diag, log_temp, out);
}

// Round 3
// 396.371 us; speedup vs baseline: 2.0810x; 2.0810x over previous
//
#include <hip/hip_runtime.h>
#include <hip/hip_bf16.h>

typedef __bf16 bf16_t;
typedef __bf16 bf16x8 __attribute__((ext_vector_type(8)));
typedef __bf16 bf16x4 __attribute__((ext_vector_type(4)));
typedef float f32x4 __attribute__((ext_vector_type(4)));

#define NB 16384
#define PP 128
#define NSPLIT 16           // col groups for logits kernel
#define CG (NB / NSPLIT)    // 1024 cols per block
#define NT (CG / 128)       // 8 B-tiles per block

__device__ inline bf16x8 ld8(const bf16_t* p) { return *(const bf16x8*)p; }

// direct global->LDS async copy, 16 B/lane (wave-uniform LDS base + lane*16)
__device__ inline void gload_lds16(const bf16_t* g, bf16_t* l) {
  __builtin_amdgcn_global_load_lds(
      (const __attribute__((address_space(1))) unsigned int*)g,
      (__attribute__((address_space(3))) unsigned int*)l, 16, 0, 0);
}

// ---------------------------------------------------------------------------
// K1: all four weight transposes (fp32 [K][128] -> bf16 [128][K]) in one launch
// ---------------------------------------------------------------------------
__global__ void transpose_all(const float* __restrict__ Wi1, const float* __restrict__ Wn1,
                              const float* __restrict__ Wi2, const float* __restrict__ Wn2,
                              bf16_t* __restrict__ Wi1t, bf16_t* __restrict__ Wn1t,
                              bf16_t* __restrict__ Wi2t, bf16_t* __restrict__ Wn2t) {
  int idx = blockIdx.x * 256 + threadIdx.x;
  if (idx < 2048 * 128) { int k = idx >> 7, n = idx & 127; Wi1t[n * 2048 + k] = (bf16_t)Wi1[idx]; return; }
  idx -= 2048 * 128;
  if (idx < 256 * 128)  { int k = idx >> 7, n = idx & 127; Wn1t[n * 256 + k]  = (bf16_t)Wn1[idx]; return; }
  idx -= 256 * 128;
  if (idx < 128 * 128)  { int k = idx >> 7, n = idx & 127; Wi2t[n * 128 + k]  = (bf16_t)Wi2[idx]; return; }
  idx -= 128 * 128;
  if (idx < 128 * 128)  { int k = idx >> 7, n = idx & 127; Wn2t[n * 128 + k]  = (bf16_t)Wn2[idx]; }
}

// ---------------------------------------------------------------------------
// K2: H = relu(X @ W1 + b1) bf16. X:[NB][K] fp32, Wt:[128][K] bf16.
// BM=32 (grid 512 -> 2 blocks/CU), BN=128, BK=64. LDS chunk^(row&7) swizzle.
// ---------------------------------------------------------------------------
__global__ __launch_bounds__(256, 2) void mlp1_kernel(
    const float* __restrict__ X, const bf16_t* __restrict__ Wt,
    const float* __restrict__ bias, bf16_t* __restrict__ H, int K) {
  __shared__ bf16_t As[32 * 64];
  __shared__ bf16_t Bs[128 * 64];
  const int t = threadIdx.x, l = t & 63, wid = t >> 6;
  const int wm = wid >> 1, wn = wid & 1;          // wave tile 16x64
  const int row0 = blockIdx.x * 32;

  f32x4 acc[4];
#pragma unroll
  for (int j = 0; j < 4; j++) acc[j] = (f32x4){0.f, 0.f, 0.f, 0.f};

  for (int k0 = 0; k0 < K; k0 += 64) {
    __syncthreads();
    // stage A: 32 rows x 16 fp32-quads -> bf16 (512 slots)
#pragma unroll
    for (int i = 0; i < 2; i++) {
      int s = t + i * 256;
      int r = s >> 4, c4 = s & 15;
      const float4 f = *(const float4*)(X + (size_t)(row0 + r) * K + k0 + c4 * 4);
      bf16x4 pk;
      pk[0] = (bf16_t)f.x; pk[1] = (bf16_t)f.y; pk[2] = (bf16_t)f.z; pk[3] = (bf16_t)f.w;
      int chunk = c4 >> 1, half = c4 & 1;
      *(bf16x4*)(As + r * 64 + (chunk ^ (r & 7)) * 8 + half * 4) = pk;
    }
    // stage B: 128 rows x 8 chunks (1024 slots)
#pragma unroll
    for (int i = 0; i < 4; i++) {
      int s = t + i * 256;
      int r = s >> 3, c = s & 7;
      bf16x8 v = ld8(Wt + (size_t)r * K + k0 + c * 8);
      *(bf16x8*)(Bs + r * 64 + (c ^ (r & 7)) * 8) = v;
    }
    __syncthreads();
#pragma unroll
    for (int ks = 0; ks < 2; ks++) {
      int r = wm * 16 + (l & 15);
      int c = ks * 4 + (l >> 4);
      bf16x8 a = ld8(As + r * 64 + (c ^ (r & 7)) * 8);
#pragma unroll
      for (int nt = 0; nt < 4; nt++) {
        int rb = wn * 64 + nt * 16 + (l & 15);
        bf16x8 b = ld8(Bs + rb * 64 + (c ^ (rb & 7)) * 8);
        acc[nt] = __builtin_amdgcn_mfma_f32_16x16x32_bf16(a, b, acc[nt], 0, 0, 0);
      }
    }
  }
  int rbase = row0 + wm * 16 + ((l >> 4) << 2);
#pragma unroll
  for (int nt = 0; nt < 4; nt++) {
    int col = wn * 64 + nt * 16 + (l & 15);
    float bv = bias[col];
#pragma unroll
    for (int r4 = 0; r4 < 4; r4++) {
      float v = acc[nt][r4] + bv;
      H[(size_t)(rbase + r4) * PP + col] = (bf16_t)fmaxf(v, 0.f);
    }
  }
}

// ---------------------------------------------------------------------------
// K3: Out = l2norm(Hin @ W2 + b2) bf16, stored CHUNK-SWIZZLED per row:
// (row,col) -> col' = ((col>>3) ^ (row&7))*8 + (col&7), so K4 can stage with
// linear global_load_lds and XOR on the read side. BM=32 (grid 512).
// ---------------------------------------------------------------------------
__global__ __launch_bounds__(256, 2) void mlp2_norm_kernel(
    const bf16_t* __restrict__ Hin, const bf16_t* __restrict__ W2t,
    const float* __restrict__ bias, bf16_t* __restrict__ Out) {
  __shared__ bf16_t As[32 * 128];
  __shared__ bf16_t Bs[128 * 128];
  __shared__ float rnorm[32];
  const int t = threadIdx.x, l = t & 63, wid = t >> 6;
  const int wm = wid >> 1, wn = wid & 1;
  const int row0 = blockIdx.x * 32;
  if (t < 32) rnorm[t] = 0.f;
#pragma unroll
  for (int i = 0; i < 2; i++) {  // A: 32 x 16 chunks
    int s = t + i * 256;
    int r = s >> 4, c = s & 15;
    bf16x8 v = ld8(Hin + (size_t)(row0 + r) * 128 + c * 8);
    *(bf16x8*)(As + r * 128 + (c ^ (r & 7)) * 8) = v;
  }
#pragma unroll
  for (int i = 0; i < 8; i++) {  // B: 128 x 16 chunks
    int s = t + i * 256;
    int r = s >> 4, c = s & 15;
    bf16x8 v = ld8(W2t + (size_t)r * 128 + c * 8);
    *(bf16x8*)(Bs + r * 128 + (c ^ (r & 7)) * 8) = v;
  }
  __syncthreads();
  f32x4 acc[4];
#pragma unroll
  for (int j = 0; j < 4; j++) acc[j] = (f32x4){0.f, 0.f, 0.f, 0.f};
#pragma unroll
  for (int ks = 0; ks < 4; ks++) {
    int r = wm * 16 + (l & 15);
    int c = ks * 4 + (l >> 4);
    bf16x8 a = ld8(As + r * 128 + (c ^ (r & 7)) * 8);
#pragma unroll
    for (int nt = 0; nt < 4; nt++) {
      int rb = wn * 64 + nt * 16 + (l & 15);
      bf16x8 b = ld8(Bs + rb * 128 + (c ^ (rb & 7)) * 8);
      acc[nt] = __builtin_amdgcn_mfma_f32_16x16x32_bf16(a, b, acc[nt], 0, 0, 0);
    }
  }
  float vv[4][4];
#pragma unroll
  for (int nt = 0; nt < 4; nt++) {
    int col = wn * 64 + nt * 16 + (l & 15);
    float bv = bias[col];
#pragma unroll
    for (int r4 = 0; r4 < 4; r4++) vv[nt][r4] = acc[nt][r4] + bv;
  }
#pragma unroll
  for (int r4 = 0; r4 < 4; r4++) {
    float p = 0.f;
#pragma unroll
    for (int nt = 0; nt < 4; nt++) p += vv[nt][r4] * vv[nt][r4];
    p += __shfl_xor(p, 1); p += __shfl_xor(p, 2);
    p += __shfl_xor(p, 4); p += __shfl_xor(p, 8);
    if ((l & 15) == 0) atomicAdd(&rnorm[wm * 16 + ((l >> 4) << 2) + r4], p);
  }
  __syncthreads();
#pragma unroll
  for (int r4 = 0; r4 < 4; r4++) {
    int rl = wm * 16 + ((l >> 4) << 2) + r4;
    float sc = 1.f / fmaxf(sqrtf(rnorm[rl]), 1e-12f);
#pragma unroll
    for (int nt = 0; nt < 4; nt++) {
      int col = wn * 64 + nt * 16 + (l & 15);
      int swcol = (((col >> 3) ^ (rl & 7)) << 3) | (col & 7);
      Out[(size_t)(row0 + rl) * 128 + swcol] = (bf16_t)(vv[nt][r4] * sc);
    }
  }
}

// ---------------------------------------------------------------------------
// K4: col-split fused logits. Block (bm, g): rows [bm*128,+128), cols
// [g*1024,+1024) as 8 tiles of 128. A resident in LDS; B streamed, staged
// ASYNC under the previous tile's exp/reduce epilogue. Row sums accumulate in
// registers; row/col partials written to unique slots (NO global atomics).
// ---------------------------------------------------------------------------
__global__ __launch_bounds__(256, 2) void logits_split(
    const bf16_t* __restrict__ IP, const bf16_t* __restrict__ NP,
    const float* __restrict__ log_temp, float* __restrict__ rowpart,
    float* __restrict__ colpart, float* __restrict__ diag) {
  __shared__ bf16_t As[128 * 128];       // 32 KB
  __shared__ bf16_t Bs[128 * 128];       // 32 KB
  __shared__ float colred[2][CG];        // 8 KB
  __shared__ float rowred[2][128];       // 1 KB
  // XCD-chunked bijective swizzle (2048 % 8 == 0): 16 consecutive bm per XCD,
  // so each XCD's L2 holds its A rows + streams the full 4 MB NP (L2-fit).
  int bid = blockIdx.x;
  int sw = (bid & 7) * (128 * NSPLIT / 8) + (bid >> 3);
  int bm = sw >> 4, g = sw & (NSPLIT - 1);
  const int t = threadIdx.x, l = t & 63, wid = t >> 6;
  const int wm = wid >> 1, wn = wid & 1;           // wave tile 64x64
  const float invt = __expf(-log_temp[0]);

  // stage A (once) + first B tile; both pre-swizzled in global, linear dest
#pragma unroll
  for (int i = 0; i < 8; i++) {
    int s = t + i * 256;
    gload_lds16(IP + (size_t)bm * (128 * 128) + s * 8, As + s * 8);
  }
#pragma unroll
  for (int i = 0; i < 8; i++) {
    int s = t + i * 256;
    gload_lds16(NP + (size_t)(g * NT) * (128 * 128) + s * 8, Bs + s * 8);
  }
  __syncthreads();

  float racc[4][4];
#pragma unroll
  for (int a = 0; a < 4; a++)
#pragma unroll
    for (int b = 0; b < 4; b++) racc[a][b] = 0.f;

#pragma unroll 1
  for (int tl = 0; tl < NT; tl++) {
    f32x4 acc[4][4];
#pragma unroll
    for (int i = 0; i < 4; i++)
#pragma unroll
      for (int j = 0; j < 4; j++) acc[i][j] = (f32x4){0.f, 0.f, 0.f, 0.f};
#pragma unroll
    for (int ks = 0; ks < 4; ks++) {
      int c = ks * 4 + (l >> 4);
      bf16x8 a[4];
#pragma unroll
      for (int mt = 0; mt < 4; mt++) {
        int r = wm * 64 + mt * 16 + (l & 15);
        a[mt] = ld8(As + r * 128 + (c ^ (r & 7)) * 8);
      }
#pragma unroll
      for (int nt = 0; nt < 4; nt++) {
        int rb = wn * 64 + nt * 16 + (l & 15);
        bf16x8 b = ld8(Bs + rb * 128 + (c ^ (rb & 7)) * 8);
#pragma unroll
        for (int mt = 0; mt < 4; mt++)
          acc[mt][nt] = __builtin_amdgcn_mfma_f32_16x16x32_bf16(a[mt], b, acc[mt][nt], 0, 0, 0);
      }
    }
    __syncthreads();  // all waves done reading Bs
    if (tl + 1 < NT) {  // async next-B stage, hidden under epilogue VALU
#pragma unroll
      for (int i = 0; i < 8; i++) {
        int s = t + i * 256;
        gload_lds16(NP + (size_t)(g * NT + tl + 1) * (128 * 128) + s * 8, Bs + s * 8);
      }
    }
    // ---- epilogue for tile tl ----
    int bn_t = g * NT + tl;
    if (bn_t == bm && wm == wn) {  // diagonal: record s/t before exp overwrite
#pragma unroll
      for (int mt = 0; mt < 4; mt++)
#pragma unroll
        for (int nt = 0; nt < 4; nt++)
#pragma unroll
          for (int r4 = 0; r4 < 4; r4++) {
            int gr = bm * 128 + wm * 64 + mt * 16 + ((l >> 4) << 2) + r4;
            int gc = bn_t * 128 + wn * 64 + nt * 16 + (l & 15);
            if (gr == gc) diag[gr] = acc[mt][nt][r4] * invt;
          }
    }
#pragma unroll
    for (int mt = 0; mt < 4; mt++)
#pragma unroll
      for (int nt = 0; nt < 4; nt++)
#pragma unroll
        for (int r4 = 0; r4 < 4; r4++)
          acc[mt][nt][r4] = __expf(fmaf(acc[mt][nt][r4], invt, -invt));
    // rows: accumulate per-lane partials across tiles (register, atomic-free)
#pragma unroll
    for (int mt = 0; mt < 4; mt++)
#pragma unroll
      for (int r4 = 0; r4 < 4; r4++)
        racc[mt][r4] += acc[mt][0][r4] + acc[mt][1][r4] + acc[mt][2][r4] + acc[mt][3][r4];
    // cols: reduce 4 lanes sharing a col, unique-slot LDS store
#pragma unroll
    for (int nt = 0; nt < 4; nt++) {
      float cs = 0.f;
#pragma unroll
      for (int mt = 0; mt < 4; mt++)
#pragma unroll
        for (int r4 = 0; r4 < 4; r4++) cs += acc[mt][nt][r4];
      cs += __shfl_xor(cs, 16); cs += __shfl_xor(cs, 32);
      if (l < 16) colred[wm][tl * 128 + wn * 64 + nt * 16 + l] = cs;
    }
    __syncthreads();  // B stage complete (barrier drains vmcnt)
  }
  // final row reduce across 16 lanes, then unique-slot LDS + global write
#pragma unroll
  for (int mt = 0; mt < 4; mt++)
#pragma unroll
    for (int r4 = 0; r4 < 4; r4++) {
      float rs = racc[mt][r4];
      rs += __shfl_xor(rs, 1); rs += __shfl_xor(rs, 2);
      rs += __shfl_xor(rs, 4); rs += __shfl_xor(rs, 8);
      if ((l & 15) == 0)
        rowred[wn][wm * 64 + mt * 16 + ((l >> 4) << 2) + r4] = rs;
    }
  __syncthreads();
  if (t < 128)
    rowpart[(size_t)g * NB + bm * 128 + t] = rowred[0][t] + rowred[1][t];
  for (int c = t; c < CG; c += 256)
    colpart[(size_t)bm * NB + g * CG + c] = colred[0][c] + colred[1][c];
}

// ---------------------------------------------------------------------------
// K5a: per-row reduce of partials -> per-block partial loss -> one atomic
// ---------------------------------------------------------------------------
__global__ void finalize1(const float* __restrict__ rowpart, const float* __restrict__ colpart,
                          const float* __restrict__ diag, float* __restrict__ lossacc) {
  int i = blockIdx.x * 64 + threadIdx.x;
  float rsum = 0.f, csum = 0.f;
#pragma unroll
  for (int g = 0; g < NSPLIT; g++) rsum += rowpart[(size_t)g * NB + i];
#pragma unroll 8
  for (int b = 0; b < 128; b++) csum += colpart[(size_t)b * NB + i];
  float v = 0.5f * (logf(rsum) + logf(csum)) - diag[i];
  for (int m = 1; m < 64; m <<= 1) v += __shfl_xor(v, m);
  if (threadIdx.x == 0) atomicAdd(lossacc, v);
}

__global__ void finalize2(const float* __restrict__ lossacc,
                          const float* __restrict__ log_temp, float* __restrict__ out) {
  out[0] = lossacc[0] / (float)NB + __expf(-log_temp[0]);
}

// ---------------------------------------------------------------------------
extern "C" void kernel_launch(void* const* d_in, const int* in_sizes, int n_in,
                              void* d_out, int out_size, void* d_ws, size_t ws_size,
                              hipStream_t stream) {
  const float* img = (const float*)d_in[0];
  const float* num = (const float*)d_in[1];
  const float* Wi1 = (const float*)d_in[2];
  const float* bi1 = (const float*)d_in[3];
  const float* Wi2 = (const float*)d_in[4];
  const float* bi2 = (const float*)d_in[5];
  const float* Wn1 = (const float*)d_in[6];
  const float* bn1 = (const float*)d_in[7];
  const float* Wn2 = (const float*)d_in[8];
  const float* bn2 = (const float*)d_in[9];
  const float* log_temp = (const float*)d_in[10];
  float* out = (float*)d_out;

  // workspace layout (peak 17.07 MB; overlaps are lifetime-disjoint):
  char* w = (char*)d_ws;
  bf16_t* ipb   = (bf16_t*)(w);                               // 0..4 MB  (swizzled)
  bf16_t* npb   = (bf16_t*)(w + (4u << 20));                  // 4..8 MB  (swizzled)
  bf16_t* h_img = (bf16_t*)(w + (8u << 20));                  // 8..12 MB
  bf16_t* h_num = (bf16_t*)(w + (12u << 20));                 // 12..16 MB
  float*  colpart = (float*)(w + (8u << 20));                 // 8..16 MB (reuses h after mlp2)
  bf16_t* Wi1t  = (bf16_t*)(w + (16u << 20));                 // 16..16.5 MB
  bf16_t* Wn1t  = (bf16_t*)(w + (16u << 20) + (512u << 10));  // 64 KB
  bf16_t* Wi2t  = (bf16_t*)(w + (16u << 20) + (576u << 10));  // 32 KB
  bf16_t* Wn2t  = (bf16_t*)(w + (16u << 20) + (640u << 10));  // 32 KB
  float*  rowpart = (float*)(w + (16u << 20));                // 16..17 MB (reuses weights after mlps)
  float*  diag  = (float*)(w + (17u << 20));                  // 64 KB
  float*  lossacc = (float*)(w + (17u << 20) + (64u << 10));  // 4 B

  hipMemsetAsync(lossacc, 0, sizeof(float), stream);

  transpose_all<<<dim3(1280), 256, 0, stream>>>(Wi1, Wn1, Wi2, Wn2, Wi1t, Wn1t, Wi2t, Wn2t);

  mlp1_kernel<<<dim3(NB / 32), 256, 0, stream>>>(img, Wi1t, bi1, h_img, 2048);
  mlp1_kernel<<<dim3(NB / 32), 256, 0, stream>>>(num, Wn1t, bn1, h_num, 256);
  mlp2_norm_kernel<<<dim3(NB / 32), 256, 0, stream>>>(h_img, Wi2t, bi2, ipb);
  mlp2_norm_kernel<<<dim3(NB / 32), 256, 0, stream>>>(h_num, Wn2t, bn2, npb);

  logits_split<<<dim3(128 * NSPLIT), 256, 0, stream>>>(ipb, npb, log_temp, rowpart, colpart, diag);
  finalize1<<<dim3(NB / 64), 64, 0, stream>>>(rowpart, colpart, diag, lossacc);
  finalize2<<<dim3(1), 1, 0, stream>>>(lossacc, log_temp, out);
}

// Round 5
// 335.109 us; speedup vs baseline: 2.4614x; 1.1828x over previous
//
#include <hip/hip_runtime.h>
#include <hip/hip_bf16.h>

typedef __bf16 bf16_t;
typedef __bf16 bf16x8 __attribute__((ext_vector_type(8)));
typedef __bf16 bf16x4 __attribute__((ext_vector_type(4)));
typedef float f32x4 __attribute__((ext_vector_type(4)));

#define NB 16384
#define PP 128
#define NSPLIT 16           // col groups for logits kernel
#define CG (NB / NSPLIT)    // 1024 cols per block
#define BNT 64              // cols per B-subtile
#define NT (CG / BNT)       // 16 B-subtiles per block

__device__ inline bf16x8 ld8(const bf16_t* p) { return *(const bf16x8*)p; }

// direct global->LDS async copy, 16 B/lane (wave-uniform LDS base + lane*16)
__device__ inline void gload_lds16(const bf16_t* g, bf16_t* l) {
  __builtin_amdgcn_global_load_lds(
      (const __attribute__((address_space(1))) unsigned int*)g,
      (__attribute__((address_space(3))) unsigned int*)l, 16, 0, 0);
}

// ---------------------------------------------------------------------------
// K1: all four weight transposes (fp32 [K][128] -> bf16 [128][K]) in one launch
// ---------------------------------------------------------------------------
__global__ void transpose_all(const float* __restrict__ Wi1, const float* __restrict__ Wn1,
                              const float* __restrict__ Wi2, const float* __restrict__ Wn2,
                              bf16_t* __restrict__ Wi1t, bf16_t* __restrict__ Wn1t,
                              bf16_t* __restrict__ Wi2t, bf16_t* __restrict__ Wn2t) {
  int idx = blockIdx.x * 256 + threadIdx.x;
  if (idx < 2048 * 128) { int k = idx >> 7, n = idx & 127; Wi1t[n * 2048 + k] = (bf16_t)Wi1[idx]; return; }
  idx -= 2048 * 128;
  if (idx < 256 * 128)  { int k = idx >> 7, n = idx & 127; Wn1t[n * 256 + k]  = (bf16_t)Wn1[idx]; return; }
  idx -= 256 * 128;
  if (idx < 128 * 128)  { int k = idx >> 7, n = idx & 127; Wi2t[n * 128 + k]  = (bf16_t)Wi2[idx]; return; }
  idx -= 128 * 128;
  if (idx < 128 * 128)  { int k = idx >> 7, n = idx & 127; Wn2t[n * 128 + k]  = (bf16_t)Wn2[idx]; }
}

// ---------------------------------------------------------------------------
// K2: combined mlp1 for img (blocks 0..511, K=2048) and num (512..1023, K=256).
// H = relu(X @ W1 + b1) bf16. BM=32, BN=128, BK=128. LDS chunk^(row&7) swizzle.
// LDS = 8KB + 32KB = 40KB -> 4 blocks/CU (exactly 160KB).
// ---------------------------------------------------------------------------
__global__ __launch_bounds__(256, 4) void mlp1_combined(
    const float* __restrict__ Ximg, const float* __restrict__ Xnum,
    const bf16_t* __restrict__ Wit, const bf16_t* __restrict__ Wnt,
    const float* __restrict__ bi, const float* __restrict__ bn,
    bf16_t* __restrict__ Himg, bf16_t* __restrict__ Hnum) {
  __shared__ bf16_t As[32 * 128];
  __shared__ bf16_t Bs[128 * 128];
  const int bid = blockIdx.x;
  const bool isnum = bid >= 512;
  const float* X = isnum ? Xnum : Ximg;
  const bf16_t* Wt = isnum ? Wnt : Wit;
  const float* bias = isnum ? bn : bi;
  bf16_t* H = isnum ? Hnum : Himg;
  const int K = isnum ? 256 : 2048;
  const int t = threadIdx.x, l = t & 63, wid = t >> 6;
  const int wm = wid >> 1, wn = wid & 1;          // wave tile 16x64
  const int row0 = (bid & 511) * 32;

  f32x4 acc[4];
#pragma unroll
  for (int j = 0; j < 4; j++) acc[j] = (f32x4){0.f, 0.f, 0.f, 0.f};

  for (int k0 = 0; k0 < K; k0 += 128) {
    __syncthreads();
    // stage A: 32 rows x 32 fp32-quads -> bf16 (1024 slots)
#pragma unroll
    for (int i = 0; i < 4; i++) {
      int s = t + i * 256;
      int r = s >> 5, c4 = s & 31;
      const float4 f = *(const float4*)(X + (size_t)(row0 + r) * K + k0 + c4 * 4);
      bf16x4 pk;
      pk[0] = (bf16_t)f.x; pk[1] = (bf16_t)f.y; pk[2] = (bf16_t)f.z; pk[3] = (bf16_t)f.w;
      int chunk = c4 >> 1, half = c4 & 1;
      *(bf16x4*)(As + r * 128 + ((chunk ^ (r & 7)) << 3) + half * 4) = pk;
    }
    // stage B: 128 rows x 16 chunks (2048 slots)
#pragma unroll
    for (int i = 0; i < 8; i++) {
      int s = t + i * 256;
      int r = s >> 4, c = s & 15;
      bf16x8 v = ld8(Wt + (size_t)r * K + k0 + c * 8);
      *(bf16x8*)(Bs + r * 128 + ((c ^ (r & 7)) << 3)) = v;
    }
    __syncthreads();
#pragma unroll
    for (int ks = 0; ks < 4; ks++) {
      int r = wm * 16 + (l & 15);
      int c = ks * 4 + (l >> 4);
      bf16x8 a = ld8(As + r * 128 + ((c ^ (r & 7)) << 3));
#pragma unroll
      for (int nt = 0; nt < 4; nt++) {
        int rb = wn * 64 + nt * 16 + (l & 15);
        bf16x8 b = ld8(Bs + rb * 128 + ((c ^ (rb & 7)) << 3));
        acc[nt] = __builtin_amdgcn_mfma_f32_16x16x32_bf16(a, b, acc[nt], 0, 0, 0);
      }
    }
  }
  int rbase = row0 + wm * 16 + ((l >> 4) << 2);
#pragma unroll
  for (int nt = 0; nt < 4; nt++) {
    int col = wn * 64 + nt * 16 + (l & 15);
    float bv = bias[col];
#pragma unroll
    for (int r4 = 0; r4 < 4; r4++) {
      float v = acc[nt][r4] + bv;
      H[(size_t)(rbase + r4) * PP + col] = (bf16_t)fmaxf(v, 0.f);
    }
  }
}

// ---------------------------------------------------------------------------
// K3: combined mlp2+l2norm for img (blocks 0..511) and num (512..1023).
// Out stored CHUNK-SWIZZLED per row: (row,col) -> col' = ((col>>3)^(row&7))*8+(col&7)
// so K4 stages with linear global_load_lds and XORs on the read side.
// ---------------------------------------------------------------------------
__global__ __launch_bounds__(256, 3) void mlp2_combined(
    const bf16_t* __restrict__ Himg, const bf16_t* __restrict__ Hnum,
    const bf16_t* __restrict__ Wi2t, const bf16_t* __restrict__ Wn2t,
    const float* __restrict__ bi2, const float* __restrict__ bn2,
    bf16_t* __restrict__ OutI, bf16_t* __restrict__ OutN) {
  __shared__ bf16_t As[32 * 128];
  __shared__ bf16_t Bs[128 * 128];
  __shared__ float rnorm[32];
  const int bid = blockIdx.x;
  const bool isnum = bid >= 512;
  const bf16_t* Hin = isnum ? Hnum : Himg;
  const bf16_t* W2t = isnum ? Wn2t : Wi2t;
  const float* bias = isnum ? bn2 : bi2;
  bf16_t* Out = isnum ? OutN : OutI;
  const int t = threadIdx.x, l = t & 63, wid = t >> 6;
  const int wm = wid >> 1, wn = wid & 1;
  const int row0 = (bid & 511) * 32;
  if (t < 32) rnorm[t] = 0.f;
#pragma unroll
  for (int i = 0; i < 2; i++) {  // A: 32 x 16 chunks
    int s = t + i * 256;
    int r = s >> 4, c = s & 15;
    bf16x8 v = ld8(Hin + (size_t)(row0 + r) * 128 + c * 8);
    *(bf16x8*)(As + r * 128 + ((c ^ (r & 7)) << 3)) = v;
  }
#pragma unroll
  for (int i = 0; i < 8; i++) {  // B: 128 x 16 chunks
    int s = t + i * 256;
    int r = s >> 4, c = s & 15;
    bf16x8 v = ld8(W2t + (size_t)r * 128 + c * 8);
    *(bf16x8*)(Bs + r * 128 + ((c ^ (r & 7)) << 3)) = v;
  }
  __syncthreads();
  f32x4 acc[4];
#pragma unroll
  for (int j = 0; j < 4; j++) acc[j] = (f32x4){0.f, 0.f, 0.f, 0.f};
#pragma unroll
  for (int ks = 0; ks < 4; ks++) {
    int r = wm * 16 + (l & 15);
    int c = ks * 4 + (l >> 4);
    bf16x8 a = ld8(As + r * 128 + ((c ^ (r & 7)) << 3));
#pragma unroll
    for (int nt = 0; nt < 4; nt++) {
      int rb = wn * 64 + nt * 16 + (l & 15);
      bf16x8 b = ld8(Bs + rb * 128 + ((c ^ (rb & 7)) << 3));
      acc[nt] = __builtin_amdgcn_mfma_f32_16x16x32_bf16(a, b, acc[nt], 0, 0, 0);
    }
  }
  float vv[4][4];
#pragma unroll
  for (int nt = 0; nt < 4; nt++) {
    int col = wn * 64 + nt * 16 + (l & 15);
    float bv = bias[col];
#pragma unroll
    for (int r4 = 0; r4 < 4; r4++) vv[nt][r4] = acc[nt][r4] + bv;
  }
#pragma unroll
  for (int r4 = 0; r4 < 4; r4++) {
    float p = 0.f;
#pragma unroll
    for (int nt = 0; nt < 4; nt++) p += vv[nt][r4] * vv[nt][r4];
    p += __shfl_xor(p, 1); p += __shfl_xor(p, 2);
    p += __shfl_xor(p, 4); p += __shfl_xor(p, 8);
    if ((l & 15) == 0) atomicAdd(&rnorm[wm * 16 + ((l >> 4) << 2) + r4], p);
  }
  __syncthreads();
#pragma unroll
  for (int r4 = 0; r4 < 4; r4++) {
    int rl = wm * 16 + ((l >> 4) << 2) + r4;
    float sc = 1.f / fmaxf(sqrtf(rnorm[rl]), 1e-12f);
#pragma unroll
    for (int nt = 0; nt < 4; nt++) {
      int col = wn * 64 + nt * 16 + (l & 15);
      int swcol = (((col >> 3) ^ (rl & 7)) << 3) | (col & 7);
      Out[(size_t)(row0 + rl) * 128 + swcol] = (bf16_t)(vv[nt][r4] * sc);
    }
  }
}

// ---------------------------------------------------------------------------
// K4 v2: col-split fused logits. Block (bm, g): rows [bm*128,+128), cols
// [g*1024,+1024) as 16 subtiles of 64. A-fragments live in REGISTERS
// (read once); the freed 32KB LDS double-buffers B (stage fully async under
// MFMA+epilogue, ONE barrier per tile). LDS 41KB -> 3 blocks/CU.
// Epilogue: exp2(pk-fma) + vectorized f32x4 reductions; no global atomics.
// ---------------------------------------------------------------------------
__global__ __launch_bounds__(256, 3) void logits_split(
    const bf16_t* __restrict__ IP, const bf16_t* __restrict__ NP,
    const float* __restrict__ log_temp, float* __restrict__ rowpart,
    float* __restrict__ colpart, float* __restrict__ diag) {
  __shared__ bf16_t BsAll[2 * BNT * 128];  // 32 KB: A staging, then B dbuf
  __shared__ float colred[2][CG];          // 8 KB
  __shared__ float rowred[2][128];         // 1 KB
  // XCD-chunked bijective swizzle: XCD x gets bm in [x*16,(x+1)*16), all g ->
  // per-XCD L2 working set = 0.5MB A-rows + 4MB NP (L2-resident).
  int bid = blockIdx.x;
  int sw = (bid & 7) * (128 * NSPLIT / 8) + (bid >> 3);
  int bm = sw >> 4, g = sw & (NSPLIT - 1);
  const int t = threadIdx.x, l = t & 63, wid = t >> 6;
  const int wm = wid >> 1, wn = wid & 1;           // wave tile 64 rows x 32 cols
  const float invt = __expf(-log_temp[0]);
  const float kk = invt * 1.44269504088896f;       // log2(e)/t

  // ---- prologue: stage A (128x128, 32KB) into BsAll, lift frags to regs ----
#pragma unroll
  for (int i = 0; i < 8; i++) {
    int s = t + i * 256;
    gload_lds16(IP + (size_t)bm * (128 * 128) + s * 8, BsAll + s * 8);
  }
  __syncthreads();
  bf16x8 af[4][4];                                  // [mt][ks], 64 VGPR
#pragma unroll
  for (int mt = 0; mt < 4; mt++) {
    int r = wm * 64 + mt * 16 + (l & 15);
#pragma unroll
    for (int ks = 0; ks < 4; ks++) {
      int c = ks * 4 + (l >> 4);
      af[mt][ks] = ld8(BsAll + r * 128 + ((c ^ (r & 7)) << 3));
    }
  }
  __syncthreads();                                  // all waves done reading A
  // stage B tile 0 into half 0
#pragma unroll
  for (int i = 0; i < 4; i++) {
    int s = t + i * 256;
    gload_lds16(NP + (size_t)(g * CG) * 128 + s * 8, BsAll + s * 8);
  }
  __syncthreads();                                  // drains vmcnt: B0 ready

  f32x4 racc[4];
#pragma unroll
  for (int a = 0; a < 4; a++) racc[a] = (f32x4){0.f, 0.f, 0.f, 0.f};

#pragma unroll 1
  for (int tl = 0; tl < NT; tl++) {
    bf16_t* Bsc = BsAll + (tl & 1) * (BNT * 128);
    if (tl + 1 < NT) {  // async-stage next tile into the other half
      bf16_t* Bsn = BsAll + ((tl + 1) & 1) * (BNT * 128);
      const bf16_t* src = NP + (size_t)(g * CG + (tl + 1) * BNT) * 128;
#pragma unroll
      for (int i = 0; i < 4; i++) {
        int s = t + i * 256;
        gload_lds16(src + s * 8, Bsn + s * 8);
      }
    }
    f32x4 acc[4][2];
#pragma unroll
    for (int i = 0; i < 4; i++)
#pragma unroll
      for (int j = 0; j < 2; j++) acc[i][j] = (f32x4){0.f, 0.f, 0.f, 0.f};
#pragma unroll
    for (int ks = 0; ks < 4; ks++) {
      int c = ks * 4 + (l >> 4);
      bf16x8 b[2];
#pragma unroll
      for (int nt = 0; nt < 2; nt++) {
        int rb = wn * 32 + nt * 16 + (l & 15);
        b[nt] = ld8(Bsc + rb * 128 + ((c ^ (rb & 7)) << 3));
      }
#pragma unroll
      for (int mt = 0; mt < 4; mt++) {
        acc[mt][0] = __builtin_amdgcn_mfma_f32_16x16x32_bf16(af[mt][ks], b[0], acc[mt][0], 0, 0, 0);
        acc[mt][1] = __builtin_amdgcn_mfma_f32_16x16x32_bf16(af[mt][ks], b[1], acc[mt][1], 0, 0, 0);
      }
    }
    // ---- epilogue for tile tl ----
    const int colbase = g * CG + tl * BNT;
    if ((colbase >> 7) == bm) {  // diagonal overlap: record s/t pre-exp
#pragma unroll
      for (int mt = 0; mt < 4; mt++)
#pragma unroll
        for (int nt = 0; nt < 2; nt++)
#pragma unroll
          for (int r4 = 0; r4 < 4; r4++) {
            int gr = bm * 128 + wm * 64 + mt * 16 + ((l >> 4) << 2) + r4;
            int gc = colbase + wn * 32 + nt * 16 + (l & 15);
            if (gr == gc) diag[gr] = acc[mt][nt][r4] * invt;
          }
    }
    // exp((s-1)/t) = exp2(s*kk - kk): packed fma + v_exp
#pragma unroll
    for (int mt = 0; mt < 4; mt++)
#pragma unroll
      for (int nt = 0; nt < 2; nt++) {
        f32x4 y = acc[mt][nt] * kk - kk;
#pragma unroll
        for (int r4 = 0; r4 < 4; r4++) acc[mt][nt][r4] = __builtin_amdgcn_exp2f(y[r4]);
      }
    // row partials: vectorized accumulate (packed adds)
#pragma unroll
    for (int mt = 0; mt < 4; mt++) racc[mt] += acc[mt][0] + acc[mt][1];
    // col partials: 4 lanes/col reduce, unique-slot LDS store
#pragma unroll
    for (int nt = 0; nt < 2; nt++) {
      f32x4 cv = (acc[0][nt] + acc[1][nt]) + (acc[2][nt] + acc[3][nt]);
      float cs = (cv[0] + cv[1]) + (cv[2] + cv[3]);
      cs += __shfl_xor(cs, 16); cs += __shfl_xor(cs, 32);
      if (l < 16) colred[wm][tl * BNT + wn * 32 + nt * 16 + l] = cs;
    }
    __syncthreads();  // stage(tl+1) drained + all reads of Bsc done
  }
  // final row reduce across the 16 lanes sharing each row
#pragma unroll
  for (int mt = 0; mt < 4; mt++)
#pragma unroll
    for (int r4 = 0; r4 < 4; r4++) {
      float rs = racc[mt][r4];
      rs += __shfl_xor(rs, 1); rs += __shfl_xor(rs, 2);
      rs += __shfl_xor(rs, 4); rs += __shfl_xor(rs, 8);
      if ((l & 15) == 0)
        rowred[wn][wm * 64 + mt * 16 + ((l >> 4) << 2) + r4] = rs;
    }
  __syncthreads();
  if (t < 128)
    rowpart[(size_t)g * NB + bm * 128 + t] = rowred[0][t] + rowred[1][t];
  for (int c = t; c < CG; c += 256)
    colpart[(size_t)bm * NB + g * CG + c] = colred[0][c] + colred[1][c];
}

// ---------------------------------------------------------------------------
// K5a: per-row reduce of partials -> per-block partial loss -> one atomic
// ---------------------------------------------------------------------------
__global__ void finalize1(const float* __restrict__ rowpart, const float* __restrict__ colpart,
                          const float* __restrict__ diag, float* __restrict__ lossacc) {
  int i = blockIdx.x * 64 + threadIdx.x;
  float rsum = 0.f, csum = 0.f;
#pragma unroll
  for (int g = 0; g < NSPLIT; g++) rsum += rowpart[(size_t)g * NB + i];
#pragma unroll 16
  for (int b = 0; b < 128; b++) csum += colpart[(size_t)b * NB + i];
  float v = 0.5f * (logf(rsum) + logf(csum)) - diag[i];
  for (int m = 1; m < 64; m <<= 1) v += __shfl_xor(v, m);
  if (threadIdx.x == 0) atomicAdd(lossacc, v);
}

__global__ void finalize2(const float* __restrict__ lossacc,
                          const float* __restrict__ log_temp, float* __restrict__ out) {
  out[0] = lossacc[0] / (float)NB + __expf(-log_temp[0]);
}

// ---------------------------------------------------------------------------
extern "C" void kernel_launch(void* const* d_in, const int* in_sizes, int n_in,
                              void* d_out, int out_size, void* d_ws, size_t ws_size,
                              hipStream_t stream) {
  const float* img = (const float*)d_in[0];
  const float* num = (const float*)d_in[1];
  const float* Wi1 = (const float*)d_in[2];
  const float* bi1 = (const float*)d_in[3];
  const float* Wi2 = (const float*)d_in[4];
  const float* bi2 = (const float*)d_in[5];
  const float* Wn1 = (const float*)d_in[6];
  const float* bn1 = (const float*)d_in[7];
  const float* Wn2 = (const float*)d_in[8];
  const float* bn2 = (const float*)d_in[9];
  const float* log_temp = (const float*)d_in[10];
  float* out = (float*)d_out;

  // workspace layout (peak 17.07 MB; overlaps are lifetime-disjoint):
  char* w = (char*)d_ws;
  bf16_t* ipb   = (bf16_t*)(w);                               // 0..4 MB  (swizzled)
  bf16_t* npb   = (bf16_t*)(w + (4u << 20));                  // 4..8 MB  (swizzled)
  bf16_t* h_img = (bf16_t*)(w + (8u << 20));                  // 8..12 MB
  bf16_t* h_num = (bf16_t*)(w + (12u << 20));                 // 12..16 MB
  float*  colpart = (float*)(w + (8u << 20));                 // 8..16 MB (reuses h after mlp2)
  bf16_t* Wi1t  = (bf16_t*)(w + (16u << 20));                 // 16..16.5 MB
  bf16_t* Wn1t  = (bf16_t*)(w + (16u << 20) + (512u << 10));  // 64 KB
  bf16_t* Wi2t  = (bf16_t*)(w + (16u << 20) + (576u << 10));  // 32 KB
  bf16_t* Wn2t  = (bf16_t*)(w + (16u << 20) + (640u << 10));  // 32 KB
  float*  rowpart = (float*)(w + (16u << 20));                // 16..17 MB (reuses weights after mlps)
  float*  diag  = (float*)(w + (17u << 20));                  // 64 KB
  float*  lossacc = (float*)(w + (17u << 20) + (64u << 10));  // 4 B

  hipMemsetAsync(lossacc, 0, sizeof(float), stream);

  transpose_all<<<dim3(1280), 256, 0, stream>>>(Wi1, Wn1, Wi2, Wn2, Wi1t, Wn1t, Wi2t, Wn2t);

  mlp1_combined<<<dim3(1024), 256, 0, stream>>>(img, num, Wi1t, Wn1t, bi1, bn1, h_img, h_num);
  mlp2_combined<<<dim3(1024), 256, 0, stream>>>(h_img, h_num, Wi2t, Wn2t, bi2, bn2, ipb, npb);

  logits_split<<<dim3(128 * NSPLIT), 256, 0, stream>>>(ipb, npb, log_temp, rowpart, colpart, diag);
  finalize1<<<dim3(NB / 64), 64, 0, stream>>>(rowpart, colpart, diag, lossacc);
  finalize2<<<dim3(1), 1, 0, stream>>>(lossacc, log_temp, out);
}